// Round 2
// baseline (849.435 us; speedup 1.0000x reference)
//
#include <hip/hip_runtime.h>
#include <hip/hip_bf16.h>

#define NN 50000
#define DIN 256
#define HC 256   // H*C
#define NH 4     // heads
#define CC 64    // per-head dim

// ---------------------------------------------------------------------------
// GEMM: h = x @ W  (fp32, 64x64 tile, BK=64, 4x4 microtile per thread)
// grid: (ceil(N/64), 4, 2)  z selects (W1->h1) vs (W2->h2)
// ---------------------------------------------------------------------------
__global__ __launch_bounds__(256) void gemm_kernel(
    const float* __restrict__ x, const float* __restrict__ W1,
    const float* __restrict__ W2, float* __restrict__ h1,
    float* __restrict__ h2) {
  const float* __restrict__ W = blockIdx.z ? W2 : W1;
  float* __restrict__ hout = blockIdx.z ? h2 : h1;
  __shared__ float As[64][68];
  __shared__ float Bs[64][68];
  const int tid = threadIdx.x;
  const int lr = tid >> 4;   // 0..15 loader row base
  const int lc = tid & 15;   // 0..15 loader float4-col
  const int ty = tid >> 4;   // 0..15 compute row group (4 rows)
  const int tx = tid & 15;   // 0..15 compute col group (4 cols)
  const int m0 = blockIdx.x * 64;
  const int n0 = blockIdx.y * 64;

  float acc[4][4] = {};

  for (int kt = 0; kt < 4; ++kt) {
    const int k0 = kt * 64;
#pragma unroll
    for (int i = 0; i < 4; ++i) {
      int r = lr + 16 * i;
      int gm = m0 + r;
      float4 av = (gm < NN)
                      ? *(const float4*)&x[(size_t)gm * DIN + k0 + 4 * lc]
                      : make_float4(0.f, 0.f, 0.f, 0.f);
      *(float4*)&As[r][4 * lc] = av;
      float4 bv = *(const float4*)&W[(size_t)(k0 + r) * HC + n0 + 4 * lc];
      *(float4*)&Bs[r][4 * lc] = bv;
    }
    __syncthreads();
#pragma unroll
    for (int kk = 0; kk < 64; ++kk) {
      float a0 = As[ty * 4 + 0][kk];
      float a1 = As[ty * 4 + 1][kk];
      float a2 = As[ty * 4 + 2][kk];
      float a3 = As[ty * 4 + 3][kk];
      float4 bv = *(const float4*)&Bs[kk][tx * 4];
      acc[0][0] += a0 * bv.x; acc[0][1] += a0 * bv.y;
      acc[0][2] += a0 * bv.z; acc[0][3] += a0 * bv.w;
      acc[1][0] += a1 * bv.x; acc[1][1] += a1 * bv.y;
      acc[1][2] += a1 * bv.z; acc[1][3] += a1 * bv.w;
      acc[2][0] += a2 * bv.x; acc[2][1] += a2 * bv.y;
      acc[2][2] += a2 * bv.z; acc[2][3] += a2 * bv.w;
      acc[3][0] += a3 * bv.x; acc[3][1] += a3 * bv.y;
      acc[3][2] += a3 * bv.z; acc[3][3] += a3 * bv.w;
    }
    __syncthreads();
  }
#pragma unroll
  for (int i = 0; i < 4; ++i) {
    int gm = m0 + ty * 4 + i;
    if (gm < NN) {
      *(float4*)&hout[(size_t)gm * HC + n0 + tx * 4] =
          make_float4(acc[i][0], acc[i][1], acc[i][2], acc[i][3]);
    }
  }
}

// ---------------------------------------------------------------------------
// es/ed: per-node attention logits for both directions.
// one wave per (n, dir, head). grid = N*8/4 blocks of 256.
// ---------------------------------------------------------------------------
__global__ __launch_bounds__(256) void esed_kernel(
    const float* __restrict__ h1, const float* __restrict__ h2,
    const float* __restrict__ as1, const float* __restrict__ ad1,
    const float* __restrict__ as2, const float* __restrict__ ad2,
    float* __restrict__ es1, float* __restrict__ ed1,
    float* __restrict__ es2, float* __restrict__ ed2) {
  int w = blockIdx.x * 4 + (threadIdx.x >> 6);
  int lane = threadIdx.x & 63;
  int n = w >> 3;
  int sel = w & 7;
  int dir = sel >> 2;
  int hd = sel & 3;
  const float* h = dir ? h2 : h1;
  const float* as = dir ? as2 : as1;
  const float* ad = dir ? ad2 : ad1;
  float* es = dir ? es2 : es1;
  float* ed = dir ? ed2 : ed1;
  float v = h[(size_t)n * HC + hd * CC + lane];
  float s = v * as[hd * CC + lane];
  float d = v * ad[hd * CC + lane];
#pragma unroll
  for (int o = 32; o; o >>= 1) {
    s += __shfl_xor(s, o);
    d += __shfl_xor(d, o);
  }
  if (lane == 0) {
    es[n * NH + hd] = s;
    ed[n * NH + hd] = d;
  }
}

// ---------------------------------------------------------------------------
// CSR build
// ---------------------------------------------------------------------------
__global__ __launch_bounds__(256) void degree_kernel(
    const int* __restrict__ ei0, const int* __restrict__ ei1,
    int* __restrict__ deg1, int* __restrict__ deg2, int E) {
  int e = blockIdx.x * 256 + threadIdx.x;
  if (e < E) {
    atomicAdd(&deg1[ei1[e]], 1);  // dir1 keyed by dst
    atomicAdd(&deg2[ei0[e]], 1);  // dir2 keyed by src
  }
}

__global__ __launch_bounds__(1024) void scan_kernel(
    const int* __restrict__ deg1, int* __restrict__ off1,
    int* __restrict__ cur1, const int* __restrict__ deg2,
    int* __restrict__ off2, int* __restrict__ cur2, int n) {
  const int* deg = blockIdx.x ? deg2 : deg1;
  int* off = blockIdx.x ? off2 : off1;
  int* cur = blockIdx.x ? cur2 : cur1;
  __shared__ int buf[1024];
  int t = threadIdx.x;
  const int strip = (n + 1023) / 1024;
  int s0 = t * strip;
  int s1 = min(n, s0 + strip);
  int sum = 0;
  for (int i = s0; i < s1; ++i) sum += deg[i];
  buf[t] = sum;
  __syncthreads();
  int x = sum;
  for (int o = 1; o < 1024; o <<= 1) {
    int tmp = (t >= o) ? buf[t - o] : 0;
    __syncthreads();
    x += tmp;
    buf[t] = x;
    __syncthreads();
  }
  int excl = x - sum;
  for (int i = s0; i < s1; ++i) {
    int d = deg[i];
    off[i] = excl;
    cur[i] = excl;
    excl += d;
  }
  if (t == 1023) off[n] = x;
}

__global__ __launch_bounds__(256) void fill_kernel(
    const int* __restrict__ ei0, const int* __restrict__ ei1,
    int* __restrict__ cur1, int* __restrict__ cur2, int* __restrict__ csr1,
    int* __restrict__ csr2, int E) {
  int e = blockIdx.x * 256 + threadIdx.x;
  if (e < E) {
    int s = ei0[e], d = ei1[e];
    csr1[atomicAdd(&cur1[d], 1)] = s;  // dir1: incoming sources of d
    csr2[atomicAdd(&cur2[s], 1)] = d;  // dir2: incoming (transposed) of s
  }
}

// ---------------------------------------------------------------------------
// Gather-aggregate: one wave per (node, head). Softmax without max-subtraction
// (logits are ~N(0,2), max ~8 over 1.8M draws; exp() safe in fp32).
// Self-loop handled explicitly; real edges via CSR.
// ---------------------------------------------------------------------------
__global__ __launch_bounds__(256) void gather_kernel(
    const float* __restrict__ h, const float* __restrict__ es,
    const float* __restrict__ ed, const float* __restrict__ b,
    const int* __restrict__ off, const int* __restrict__ csr,
    float* __restrict__ out, int accumulate) {
  int w = blockIdx.x * 4 + (threadIdx.x >> 6);
  int lane = threadIdx.x & 63;
  int n = w >> 2;
  int hd = w & 3;
  float esn = es[n * NH + hd];
  float edn = ed[n * NH + hd];
  float e0 = esn + edn;
  e0 = e0 >= 0.f ? e0 : 0.2f * e0;
  float wsum = expf(e0);
  int hoff = hd * CC + lane;
  float acc = wsum * h[(size_t)n * HC + hoff];
  int beg = off[n], end = off[n + 1];
  for (int j = beg; j < end; ++j) {
    int s = csr[j];
    float el = es[s * NH + hd] + edn;
    el = el >= 0.f ? el : 0.2f * el;
    float wg = expf(el);
    wsum += wg;
    acc += wg * h[(size_t)s * HC + hoff];
  }
  float res = 0.5f * (acc / wsum + b[hoff]);
  size_t oi = (size_t)n * HC + hoff;
  if (accumulate)
    out[oi] += res;
  else
    out[oi] = res;
}

// ---------------------------------------------------------------------------
extern "C" void kernel_launch(void* const* d_in, const int* in_sizes, int n_in,
                              void* d_out, int out_size, void* d_ws,
                              size_t ws_size, hipStream_t stream) {
  const float* x = (const float*)d_in[0];
  const int* ei = (const int*)d_in[1];
  const int E = in_sizes[1] / 2;
  const float* W1 = (const float*)d_in[2];
  const float* as1 = (const float*)d_in[3];
  const float* ad1 = (const float*)d_in[4];
  const float* b1 = (const float*)d_in[5];
  const float* W2 = (const float*)d_in[6];
  const float* as2 = (const float*)d_in[7];
  const float* ad2 = (const float*)d_in[8];
  const float* b2 = (const float*)d_in[9];
  float* out = (float*)d_out;
  const int* ei0 = ei;
  const int* ei1 = ei + E;

  // workspace layout (fp32/int32 elements)
  float* ws = (float*)d_ws;
  float* h1 = ws;                      // N*HC
  float* h2 = h1 + (size_t)NN * HC;    // N*HC
  float* es1 = h2 + (size_t)NN * HC;   // N*NH
  float* ed1 = es1 + NN * NH;
  float* es2 = ed1 + NN * NH;
  float* ed2 = es2 + NN * NH;
  int* deg1 = (int*)(ed2 + NN * NH);   // N
  int* deg2 = deg1 + NN;               // N (contiguous with deg1 for memset)
  int* off1 = deg2 + NN;               // N+1
  int* off2 = off1 + (NN + 1);         // N+1
  int* cur1 = off2 + (NN + 1);         // N
  int* cur2 = cur1 + NN;               // N
  int* csr1 = cur2 + NN;               // E
  int* csr2 = csr1 + E;                // E

  hipMemsetAsync(deg1, 0, 2 * NN * sizeof(int), stream);

  dim3 ggrid((NN + 63) / 64, 4, 2);
  gemm_kernel<<<ggrid, 256, 0, stream>>>(x, W1, W2, h1, h2);

  esed_kernel<<<NN * 8 / 4, 256, 0, stream>>>(h1, h2, as1, ad1, as2, ad2, es1,
                                              ed1, es2, ed2);

  degree_kernel<<<(E + 255) / 256, 256, 0, stream>>>(ei0, ei1, deg1, deg2, E);
  scan_kernel<<<2, 1024, 0, stream>>>(deg1, off1, cur1, deg2, off2, cur2, NN);
  fill_kernel<<<(E + 255) / 256, 256, 0, stream>>>(ei0, ei1, cur1, cur2, csr1,
                                                   csr2, E);

  gather_kernel<<<NN, 256, 0, stream>>>(h1, es1, ed1, b1, off1, csr1, out, 0);
  gather_kernel<<<NN, 256, 0, stream>>>(h2, es2, ed2, b2, off2, csr2, out, 1);
}

// Round 9
// 481.252 us; speedup vs baseline: 1.7651x; 1.7651x over previous
//
#include <hip/hip_runtime.h>
#include <hip/hip_bf16.h>

#define NN 50000
#define DIN 256
#define HC 256   // H*C per direction
#define NH 4     // heads
#define CC 64    // per-head dim

typedef __attribute__((ext_vector_type(8))) short short8;
typedef __attribute__((ext_vector_type(4))) float f32x4;

__device__ inline unsigned short f2bf(float f) {
  unsigned int u = __builtin_bit_cast(unsigned int, f);
  u = (u + 0x7FFF + ((u >> 16) & 1)) >> 16;  // RTNE, no NaN inputs here
  return (unsigned short)u;
}
__device__ inline float bf2f(unsigned short u) {
  return __builtin_bit_cast(float, ((unsigned int)u) << 16);
}

// ---------------------------------------------------------------------------
// x (fp32) -> xb (bf16). 12.8M elements, 4 per thread.
// ---------------------------------------------------------------------------
__global__ __launch_bounds__(256) void convert_x_kernel(
    const float* __restrict__ x, unsigned short* __restrict__ xb) {
  int i = (blockIdx.x * 256 + threadIdx.x) * 4;
  float4 v = *(const float4*)&x[i];
  ushort4 o;
  o.x = f2bf(v.x); o.y = f2bf(v.y); o.z = f2bf(v.z); o.w = f2bf(v.w);
  *(ushort4*)&xb[i] = o;
}

// ---------------------------------------------------------------------------
// WbT[n][k] = (n<256 ? W1 : W2)[k][n%256], bf16. 512x256 elements.
// ---------------------------------------------------------------------------
__global__ __launch_bounds__(256) void wbt_kernel(
    const float* __restrict__ W1, const float* __restrict__ W2,
    unsigned short* __restrict__ wbt) {
  int idx = blockIdx.x * 256 + threadIdx.x;  // 131072
  int n = idx >> 8;
  int k = idx & 255;
  float v = (n < HC) ? W1[k * HC + n] : W2[k * HC + (n - HC)];
  wbt[n * DIN + k] = f2bf(v);
}

// ---------------------------------------------------------------------------
// MFMA GEMM: h[50000][512] (bf16) = xb[50000][256] @ [W1|W2] via WbT.
// 128x128 block tile, 4 waves (2x2), each wave 64x64 = 4x4 frags of 16x16x32.
// No LDS: A/B fragments are contiguous-K 16B loads from L3/L2-resident data.
// ---------------------------------------------------------------------------
__global__ __launch_bounds__(256) void gemm_mfma_kernel(
    const unsigned short* __restrict__ xb,
    const unsigned short* __restrict__ wbt, unsigned short* __restrict__ h) {
  const int tid = threadIdx.x;
  const int lane = tid & 63;
  const int wid = tid >> 6;
  const int wr = wid >> 1;  // 0..1
  const int wc = wid & 1;   // 0..1
  const int m0 = blockIdx.x * 128 + wr * 64;
  const int n0 = blockIdx.y * 128 + wc * 64;
  const int fr = lane & 15;
  const int kbase = (lane >> 4) * 8;

  f32x4 acc[4][4];
#pragma unroll
  for (int m = 0; m < 4; ++m)
#pragma unroll
    for (int n = 0; n < 4; ++n) acc[m][n] = (f32x4){0.f, 0.f, 0.f, 0.f};

  int arow[4];
  bool rowok[4];
#pragma unroll
  for (int m = 0; m < 4; ++m) {
    arow[m] = m0 + m * 16 + fr;
    rowok[m] = arow[m] < NN;
  }
  const short8 zero8 = {0, 0, 0, 0, 0, 0, 0, 0};

  for (int k0 = 0; k0 < DIN; k0 += 32) {
    short8 a[4], b[4];
#pragma unroll
    for (int m = 0; m < 4; ++m)
      a[m] = rowok[m] ? *(const short8*)&xb[(size_t)arow[m] * DIN + k0 + kbase]
                      : zero8;
#pragma unroll
    for (int n = 0; n < 4; ++n)
      b[n] = *(const short8*)&wbt[(size_t)(n0 + n * 16 + fr) * DIN + k0 + kbase];
#pragma unroll
    for (int m = 0; m < 4; ++m)
#pragma unroll
      for (int n = 0; n < 4; ++n)
        acc[m][n] = __builtin_amdgcn_mfma_f32_16x16x32_bf16(a[m], b[n],
                                                            acc[m][n], 0, 0, 0);
  }

  // C/D layout: col = lane&15, row = (lane>>4)*4 + j  [m89-verified]
#pragma unroll
  for (int m = 0; m < 4; ++m) {
#pragma unroll
    for (int j = 0; j < 4; ++j) {
      int r = m0 + m * 16 + (lane >> 4) * 4 + j;
      if (r < NN) {
#pragma unroll
        for (int n = 0; n < 4; ++n) {
          h[(size_t)r * 512 + n0 + n * 16 + fr] = f2bf(acc[m][n][j]);
        }
      }
    }
  }
}

// ---------------------------------------------------------------------------
// es/ed for both directions from bf16 h. One wave per (n, dir).
// lane covers 4 contiguous elems; head = lane>>4; reduce within 16-lane group.
// ---------------------------------------------------------------------------
__global__ __launch_bounds__(256) void esed_kernel(
    const unsigned short* __restrict__ h, const float* __restrict__ as1,
    const float* __restrict__ ad1, const float* __restrict__ as2,
    const float* __restrict__ ad2, float* __restrict__ es1,
    float* __restrict__ ed1, float* __restrict__ es2,
    float* __restrict__ ed2) {
  int w = blockIdx.x * 4 + (threadIdx.x >> 6);  // 100000 waves
  int lane = threadIdx.x & 63;
  int n = w >> 1;
  int d = w & 1;
  const float* as = d ? as2 : as1;
  const float* ad = d ? ad2 : ad1;
  float* es = d ? es2 : es1;
  float* ed = d ? ed2 : ed1;
  ushort4 hv = *(const ushort4*)&h[(size_t)n * 512 + d * HC + lane * 4];
  float4 av = *(const float4*)&as[lane * 4];
  float4 dv = *(const float4*)&ad[lane * 4];
  float hf0 = bf2f(hv.x), hf1 = bf2f(hv.y), hf2 = bf2f(hv.z), hf3 = bf2f(hv.w);
  float s = hf0 * av.x + hf1 * av.y + hf2 * av.z + hf3 * av.w;
  float dd = hf0 * dv.x + hf1 * dv.y + hf2 * dv.z + hf3 * dv.w;
#pragma unroll
  for (int o = 1; o < 16; o <<= 1) {
    s += __shfl_xor(s, o);
    dd += __shfl_xor(dd, o);
  }
  if ((lane & 15) == 0) {
    int hd = lane >> 4;
    es[n * NH + hd] = s;
    ed[n * NH + hd] = dd;
  }
}

// ---------------------------------------------------------------------------
// CSR build
// ---------------------------------------------------------------------------
__global__ __launch_bounds__(256) void degree_kernel(
    const int* __restrict__ ei0, const int* __restrict__ ei1,
    int* __restrict__ deg1, int* __restrict__ deg2, int E) {
  int e = blockIdx.x * 256 + threadIdx.x;
  if (e < E) {
    atomicAdd(&deg1[ei1[e]], 1);
    atomicAdd(&deg2[ei0[e]], 1);
  }
}

__global__ __launch_bounds__(1024) void scan_kernel(
    const int* __restrict__ deg1, int* __restrict__ off1,
    int* __restrict__ cur1, const int* __restrict__ deg2,
    int* __restrict__ off2, int* __restrict__ cur2, int n) {
  const int* deg = blockIdx.x ? deg2 : deg1;
  int* off = blockIdx.x ? off2 : off1;
  int* cur = blockIdx.x ? cur2 : cur1;
  __shared__ int buf[1024];
  int t = threadIdx.x;
  const int strip = (n + 1023) / 1024;
  int s0 = t * strip;
  int s1 = min(n, s0 + strip);
  int sum = 0;
  for (int i = s0; i < s1; ++i) sum += deg[i];
  buf[t] = sum;
  __syncthreads();
  int x = sum;
  for (int o = 1; o < 1024; o <<= 1) {
    int tmp = (t >= o) ? buf[t - o] : 0;
    __syncthreads();
    x += tmp;
    buf[t] = x;
    __syncthreads();
  }
  int excl = x - sum;
  for (int i = s0; i < s1; ++i) {
    int d = deg[i];
    off[i] = excl;
    cur[i] = excl;
    excl += d;
  }
  if (t == 1023) off[n] = x;
}

__global__ __launch_bounds__(256) void fill_kernel(
    const int* __restrict__ ei0, const int* __restrict__ ei1,
    int* __restrict__ cur1, int* __restrict__ cur2, int* __restrict__ csr1,
    int* __restrict__ csr2, int E) {
  int e = blockIdx.x * 256 + threadIdx.x;
  if (e < E) {
    int s = ei0[e], d = ei1[e];
    csr1[atomicAdd(&cur1[d], 1)] = s;
    csr2[atomicAdd(&cur2[s], 1)] = d;
  }
}

// ---------------------------------------------------------------------------
// Fused gather: one wave per node, all 4 heads, both directions.
// lane -> 4 contiguous floats of the 256-wide half-row; head = lane>>4.
// Softmax without max-pass (logits ~N(0,2); exp safe in fp32).
// ---------------------------------------------------------------------------
__device__ inline void gat_side(int n, int lane, int hd,
                                const unsigned short* __restrict__ h, int half,
                                const float* __restrict__ es,
                                const float* __restrict__ ed,
                                const int* __restrict__ off,
                                const int* __restrict__ csr, float4& res) {
  float edn = ed[n * NH + hd];
  float e0 = es[n * NH + hd] + edn;
  e0 = e0 >= 0.f ? e0 : 0.2f * e0;
  float w0 = __expf(e0);
  size_t hoff = (size_t)half * HC + lane * 4;
  ushort4 hv = *(const ushort4*)&h[(size_t)n * 512 + hoff];
  float wsum = w0;
  float ax = w0 * bf2f(hv.x), ay = w0 * bf2f(hv.y);
  float az = w0 * bf2f(hv.z), aw = w0 * bf2f(hv.w);
  int beg = off[n], end = off[n + 1];
  for (int j = beg; j < end; ++j) {
    int s = csr[j];
    float el = es[s * NH + hd] + edn;
    el = el >= 0.f ? el : 0.2f * el;
    float wg = __expf(el);
    wsum += wg;
    ushort4 sv = *(const ushort4*)&h[(size_t)s * 512 + hoff];
    ax += wg * bf2f(sv.x);
    ay += wg * bf2f(sv.y);
    az += wg * bf2f(sv.z);
    aw += wg * bf2f(sv.w);
  }
  float inv = 1.f / wsum;
  res.x = ax * inv; res.y = ay * inv; res.z = az * inv; res.w = aw * inv;
}

__global__ __launch_bounds__(256) void gather_kernel(
    const unsigned short* __restrict__ h, const float* __restrict__ es1,
    const float* __restrict__ ed1, const float* __restrict__ es2,
    const float* __restrict__ ed2, const float* __restrict__ b1,
    const float* __restrict__ b2, const int* __restrict__ off1,
    const int* __restrict__ csr1, const int* __restrict__ off2,
    const int* __restrict__ csr2, float* __restrict__ out) {
  int n = blockIdx.x * 4 + (threadIdx.x >> 6);  // NN = 12500*4 exactly
  int lane = threadIdx.x & 63;
  int hd = lane >> 4;
  float4 r1, r2;
  gat_side(n, lane, hd, h, 0, es1, ed1, off1, csr1, r1);
  gat_side(n, lane, hd, h, 1, es2, ed2, off2, csr2, r2);
  float4 bv1 = *(const float4*)&b1[lane * 4];
  float4 bv2 = *(const float4*)&b2[lane * 4];
  float4 o;
  o.x = 0.5f * (r1.x + bv1.x + r2.x + bv2.x);
  o.y = 0.5f * (r1.y + bv1.y + r2.y + bv2.y);
  o.z = 0.5f * (r1.z + bv1.z + r2.z + bv2.z);
  o.w = 0.5f * (r1.w + bv1.w + r2.w + bv2.w);
  *(float4*)&out[(size_t)n * HC + lane * 4] = o;
}

// ---------------------------------------------------------------------------
extern "C" void kernel_launch(void* const* d_in, const int* in_sizes, int n_in,
                              void* d_out, int out_size, void* d_ws,
                              size_t ws_size, hipStream_t stream) {
  const float* x = (const float*)d_in[0];
  const int* ei = (const int*)d_in[1];
  const int E = in_sizes[1] / 2;
  const float* W1 = (const float*)d_in[2];
  const float* as1 = (const float*)d_in[3];
  const float* ad1 = (const float*)d_in[4];
  const float* b1 = (const float*)d_in[5];
  const float* W2 = (const float*)d_in[6];
  const float* as2 = (const float*)d_in[7];
  const float* ad2 = (const float*)d_in[8];
  const float* b2 = (const float*)d_in[9];
  float* out = (float*)d_out;
  const int* ei0 = ei;
  const int* ei1 = ei + E;

  // workspace layout
  unsigned short* xb = (unsigned short*)d_ws;       // N*256 bf16
  unsigned short* h = xb + (size_t)NN * DIN;        // N*512 bf16
  unsigned short* wbt = h + (size_t)NN * 512;       // 512*256 bf16
  float* es1 = (float*)(wbt + 512 * DIN);           // N*4 each
  float* ed1 = es1 + NN * NH;
  float* es2 = ed1 + NN * NH;
  float* ed2 = es2 + NN * NH;
  int* deg1 = (int*)(ed2 + NN * NH);
  int* deg2 = deg1 + NN;
  int* off1 = deg2 + NN;
  int* off2 = off1 + (NN + 1);
  int* cur1 = off2 + (NN + 1);
  int* cur2 = cur1 + NN;
  int* csr1 = cur2 + NN;
  int* csr2 = csr1 + E;

  hipMemsetAsync(deg1, 0, 2 * NN * sizeof(int), stream);

  convert_x_kernel<<<NN * DIN / 1024, 256, 0, stream>>>(x, xb);
  wbt_kernel<<<512, 256, 0, stream>>>(W1, W2, wbt);
  degree_kernel<<<(E + 255) / 256, 256, 0, stream>>>(ei0, ei1, deg1, deg2, E);

  dim3 ggrid((NN + 127) / 128, 4);
  gemm_mfma_kernel<<<ggrid, 256, 0, stream>>>(xb, wbt, h);

  esed_kernel<<<NN * 2 / 4, 256, 0, stream>>>(h, as1, ad1, as2, ad2, es1, ed1,
                                              es2, ed2);
  scan_kernel<<<2, 1024, 0, stream>>>(deg1, off1, cur1, deg2, off2, cur2, NN);
  fill_kernel<<<(E + 255) / 256, 256, 0, stream>>>(ei0, ei1, cur1, cur2, csr1,
                                                   csr2, E);

  gather_kernel<<<NN / 4, 256, 0, stream>>>(h, es1, ed1, es2, ed2, b1, b2,
                                            off1, csr1, off2, csr2, out);
}

// Round 12
// 379.030 us; speedup vs baseline: 2.2411x; 1.2697x over previous
//
#include <hip/hip_runtime.h>
#include <hip/hip_bf16.h>

#define NN 50000
#define DIN 256
#define HC 256   // H*C per direction
#define NH 4     // heads
#define CC 64    // per-head dim
#define NBLK 49  // ceil(NN/1024) chunks per direction

typedef __attribute__((ext_vector_type(8))) short short8;
typedef __attribute__((ext_vector_type(4))) float f32x4;

__device__ inline unsigned short f2bf(float f) {
  unsigned int u = __builtin_bit_cast(unsigned int, f);
  u = (u + 0x7FFF + ((u >> 16) & 1)) >> 16;  // RTNE, no NaN inputs here
  return (unsigned short)u;
}
__device__ inline float bf2f(unsigned short u) {
  return __builtin_bit_cast(float, ((unsigned int)u) << 16);
}

// ---------------------------------------------------------------------------
// x (fp32) -> xb (bf16). 12.8M elements, 4 per thread.
// ---------------------------------------------------------------------------
__global__ __launch_bounds__(256) void convert_x_kernel(
    const float* __restrict__ x, unsigned short* __restrict__ xb) {
  int i = (blockIdx.x * 256 + threadIdx.x) * 4;
  float4 v = *(const float4*)&x[i];
  ushort4 o;
  o.x = f2bf(v.x); o.y = f2bf(v.y); o.z = f2bf(v.z); o.w = f2bf(v.w);
  *(ushort4*)&xb[i] = o;
}

// ---------------------------------------------------------------------------
// WbT[n][k] = (n<256 ? W1 : W2)[k][n%256], bf16. 512x256 elements.
// ---------------------------------------------------------------------------
__global__ __launch_bounds__(256) void wbt_kernel(
    const float* __restrict__ W1, const float* __restrict__ W2,
    unsigned short* __restrict__ wbt) {
  int idx = blockIdx.x * 256 + threadIdx.x;  // 131072
  int n = idx >> 8;
  int k = idx & 255;
  float v = (n < HC) ? W1[k * HC + n] : W2[k * HC + (n - HC)];
  wbt[n * DIN + k] = f2bf(v);
}

// ---------------------------------------------------------------------------
// MFMA GEMM: h[50000][512] (bf16) = xb[50000][256] @ [W1|W2] via WbT.
// 128x128 block tile, 4 waves (2x2), each wave 64x64 = 4x4 frags of 16x16x32.
// ---------------------------------------------------------------------------
__global__ __launch_bounds__(256) void gemm_mfma_kernel(
    const unsigned short* __restrict__ xb,
    const unsigned short* __restrict__ wbt, unsigned short* __restrict__ h) {
  const int tid = threadIdx.x;
  const int lane = tid & 63;
  const int wid = tid >> 6;
  const int wr = wid >> 1;  // 0..1
  const int wc = wid & 1;   // 0..1
  const int m0 = blockIdx.x * 128 + wr * 64;
  const int n0 = blockIdx.y * 128 + wc * 64;
  const int fr = lane & 15;
  const int kbase = (lane >> 4) * 8;

  f32x4 acc[4][4];
#pragma unroll
  for (int m = 0; m < 4; ++m)
#pragma unroll
    for (int n = 0; n < 4; ++n) acc[m][n] = (f32x4){0.f, 0.f, 0.f, 0.f};

  int arow[4];
  bool rowok[4];
#pragma unroll
  for (int m = 0; m < 4; ++m) {
    arow[m] = m0 + m * 16 + fr;
    rowok[m] = arow[m] < NN;
  }
  const short8 zero8 = {0, 0, 0, 0, 0, 0, 0, 0};

  for (int k0 = 0; k0 < DIN; k0 += 32) {
    short8 a[4], b[4];
#pragma unroll
    for (int m = 0; m < 4; ++m)
      a[m] = rowok[m] ? *(const short8*)&xb[(size_t)arow[m] * DIN + k0 + kbase]
                      : zero8;
#pragma unroll
    for (int n = 0; n < 4; ++n)
      b[n] = *(const short8*)&wbt[(size_t)(n0 + n * 16 + fr) * DIN + k0 + kbase];
#pragma unroll
    for (int m = 0; m < 4; ++m)
#pragma unroll
      for (int n = 0; n < 4; ++n)
        acc[m][n] = __builtin_amdgcn_mfma_f32_16x16x32_bf16(a[m], b[n],
                                                            acc[m][n], 0, 0, 0);
  }

  // C/D layout: col = lane&15, row = (lane>>4)*4 + j  [m89-verified]
#pragma unroll
  for (int m = 0; m < 4; ++m) {
#pragma unroll
    for (int j = 0; j < 4; ++j) {
      int r = m0 + m * 16 + (lane >> 4) * 4 + j;
      if (r < NN) {
#pragma unroll
        for (int n = 0; n < 4; ++n) {
          h[(size_t)r * 512 + n0 + n * 16 + fr] = f2bf(acc[m][n][j]);
        }
      }
    }
  }
}

// ---------------------------------------------------------------------------
// es/ed for both directions from bf16 h. One wave per (n, dir).
// ---------------------------------------------------------------------------
__global__ __launch_bounds__(256) void esed_kernel(
    const unsigned short* __restrict__ h, const float* __restrict__ as1,
    const float* __restrict__ ad1, const float* __restrict__ as2,
    const float* __restrict__ ad2, float* __restrict__ es1,
    float* __restrict__ ed1, float* __restrict__ es2,
    float* __restrict__ ed2) {
  int w = blockIdx.x * 4 + (threadIdx.x >> 6);  // 100000 waves
  int lane = threadIdx.x & 63;
  int n = w >> 1;
  int d = w & 1;
  const float* as = d ? as2 : as1;
  const float* ad = d ? ad2 : ad1;
  float* es = d ? es2 : es1;
  float* ed = d ? ed2 : ed1;
  ushort4 hv = *(const ushort4*)&h[(size_t)n * 512 + d * HC + lane * 4];
  float4 av = *(const float4*)&as[lane * 4];
  float4 dv = *(const float4*)&ad[lane * 4];
  float hf0 = bf2f(hv.x), hf1 = bf2f(hv.y), hf2 = bf2f(hv.z), hf3 = bf2f(hv.w);
  float s = hf0 * av.x + hf1 * av.y + hf2 * av.z + hf3 * av.w;
  float dd = hf0 * dv.x + hf1 * dv.y + hf2 * dv.z + hf3 * dv.w;
#pragma unroll
  for (int o = 1; o < 16; o <<= 1) {
    s += __shfl_xor(s, o);
    dd += __shfl_xor(dd, o);
  }
  if ((lane & 15) == 0) {
    int hd = lane >> 4;
    es[n * NH + hd] = s;
    ed[n * NH + hd] = dd;
  }
}

// ---------------------------------------------------------------------------
// CSR build: degree -> hierarchical scan (3 small kernels) -> fill
// ---------------------------------------------------------------------------
__global__ __launch_bounds__(256) void degree_kernel(
    const int* __restrict__ ei0, const int* __restrict__ ei1,
    int* __restrict__ deg1, int* __restrict__ deg2, int E) {
  int e = blockIdx.x * 256 + threadIdx.x;
  if (e < E) {
    atomicAdd(&deg1[ei1[e]], 1);
    atomicAdd(&deg2[ei0[e]], 1);
  }
}

// stage 1: per-1024-chunk sums. grid = 2*NBLK blocks of 256.
__global__ __launch_bounds__(256) void bsum_kernel(
    const int* __restrict__ deg1, const int* __restrict__ deg2,
    int* __restrict__ bsum) {
  int b = blockIdx.x;  // 0..2*NBLK-1
  int dir = (b >= NBLK);
  int cb = dir ? b - NBLK : b;
  const int* deg = dir ? deg2 : deg1;
  int t = threadIdx.x;
  int base = cb * 1024 + t * 4;
  int s = 0;
#pragma unroll
  for (int k = 0; k < 4; ++k) {
    int i = base + k;
    if (i < NN) s += deg[i];
  }
#pragma unroll
  for (int o = 32; o; o >>= 1) s += __shfl_down(s, o);
  __shared__ int ws[4];
  int lane = t & 63, w = t >> 6;
  if (lane == 0) ws[w] = s;
  __syncthreads();
  if (t == 0) bsum[b] = ws[0] + ws[1] + ws[2] + ws[3];
}

// stage 2: exclusive scan of NBLK chunk sums per dir. 1 block, 2 waves.
__global__ __launch_bounds__(128) void bscan_kernel(int* __restrict__ bsum) {
  int t = threadIdx.x;  // 0..127
  int w = t >> 6, lane = t & 63;
  int idx = w * NBLK + lane;
  int v = (lane < NBLK) ? bsum[idx] : 0;
  int x = v;
#pragma unroll
  for (int o = 1; o < 64; o <<= 1) {
    int y = __shfl_up(x, o);
    if (lane >= o) x += y;
  }
  if (lane < NBLK) bsum[idx] = x - v;  // exclusive
}

// stage 3: write off/cur. same geometry as stage 1.
__global__ __launch_bounds__(256) void offsets_kernel(
    const int* __restrict__ deg1, const int* __restrict__ deg2,
    const int* __restrict__ bsum, int* __restrict__ off1,
    int* __restrict__ cur1, int* __restrict__ off2, int* __restrict__ cur2,
    int E) {
  int b = blockIdx.x;
  int dir = (b >= NBLK);
  int cb = dir ? b - NBLK : b;
  const int* deg = dir ? deg2 : deg1;
  int* off = dir ? off2 : off1;
  int* cur = dir ? cur2 : cur1;
  int t = threadIdx.x;
  int base = cb * 1024 + t * 4;
  int d[4];
  int s = 0;
#pragma unroll
  for (int k = 0; k < 4; ++k) {
    int i = base + k;
    d[k] = (i < NN) ? deg[i] : 0;
    s += d[k];
  }
  int lane = t & 63, w = t >> 6;
  int x = s;
#pragma unroll
  for (int o = 1; o < 64; o <<= 1) {
    int y = __shfl_up(x, o);
    if (lane >= o) x += y;
  }
  __shared__ int ws[4];
  if (lane == 63) ws[w] = x;
  __syncthreads();
  int woff = 0;
  for (int i = 0; i < w; ++i) woff += ws[i];
  int excl = bsum[b] + woff + (x - s);
#pragma unroll
  for (int k = 0; k < 4; ++k) {
    int i = base + k;
    if (i < NN) {
      off[i] = excl;
      cur[i] = excl;
      excl += d[k];
    }
  }
  if (b == 0 && t == 0) {  // both CSRs have exactly E entries
    off1[NN] = E;
    off2[NN] = E;
  }
}

__global__ __launch_bounds__(256) void fill_kernel(
    const int* __restrict__ ei0, const int* __restrict__ ei1,
    int* __restrict__ cur1, int* __restrict__ cur2, int* __restrict__ csr1,
    int* __restrict__ csr2, int E) {
  int e = blockIdx.x * 256 + threadIdx.x;
  if (e < E) {
    int s = ei0[e], d = ei1[e];
    csr1[atomicAdd(&cur1[d], 1)] = s;
    csr2[atomicAdd(&cur2[s], 1)] = d;
  }
}

// ---------------------------------------------------------------------------
// Fused gather: one wave per node, all 4 heads, both directions.
// ---------------------------------------------------------------------------
__device__ inline void gat_side(int n, int lane, int hd,
                                const unsigned short* __restrict__ h, int half,
                                const float* __restrict__ es,
                                const float* __restrict__ ed,
                                const int* __restrict__ off,
                                const int* __restrict__ csr, float4& res) {
  float edn = ed[n * NH + hd];
  float e0 = es[n * NH + hd] + edn;
  e0 = e0 >= 0.f ? e0 : 0.2f * e0;
  float w0 = __expf(e0);
  size_t hoff = (size_t)half * HC + lane * 4;
  ushort4 hv = *(const ushort4*)&h[(size_t)n * 512 + hoff];
  float wsum = w0;
  float ax = w0 * bf2f(hv.x), ay = w0 * bf2f(hv.y);
  float az = w0 * bf2f(hv.z), aw = w0 * bf2f(hv.w);
  int beg = off[n], end = off[n + 1];
  for (int j = beg; j < end; ++j) {
    int s = csr[j];
    float el = es[s * NH + hd] + edn;
    el = el >= 0.f ? el : 0.2f * el;
    float wg = __expf(el);
    wsum += wg;
    ushort4 sv = *(const ushort4*)&h[(size_t)s * 512 + hoff];
    ax += wg * bf2f(sv.x);
    ay += wg * bf2f(sv.y);
    az += wg * bf2f(sv.z);
    aw += wg * bf2f(sv.w);
  }
  float inv = 1.f / wsum;
  res.x = ax * inv; res.y = ay * inv; res.z = az * inv; res.w = aw * inv;
}

__global__ __launch_bounds__(256) void gather_kernel(
    const unsigned short* __restrict__ h, const float* __restrict__ es1,
    const float* __restrict__ ed1, const float* __restrict__ es2,
    const float* __restrict__ ed2, const float* __restrict__ b1,
    const float* __restrict__ b2, const int* __restrict__ off1,
    const int* __restrict__ csr1, const int* __restrict__ off2,
    const int* __restrict__ csr2, float* __restrict__ out) {
  int n = blockIdx.x * 4 + (threadIdx.x >> 6);  // NN = 12500*4 exactly
  int lane = threadIdx.x & 63;
  int hd = lane >> 4;
  float4 r1, r2;
  gat_side(n, lane, hd, h, 0, es1, ed1, off1, csr1, r1);
  gat_side(n, lane, hd, h, 1, es2, ed2, off2, csr2, r2);
  float4 bv1 = *(const float4*)&b1[lane * 4];
  float4 bv2 = *(const float4*)&b2[lane * 4];
  float4 o;
  o.x = 0.5f * (r1.x + bv1.x + r2.x + bv2.x);
  o.y = 0.5f * (r1.y + bv1.y + r2.y + bv2.y);
  o.z = 0.5f * (r1.z + bv1.z + r2.z + bv2.z);
  o.w = 0.5f * (r1.w + bv1.w + r2.w + bv2.w);
  *(float4*)&out[(size_t)n * HC + lane * 4] = o;
}

// ---------------------------------------------------------------------------
extern "C" void kernel_launch(void* const* d_in, const int* in_sizes, int n_in,
                              void* d_out, int out_size, void* d_ws,
                              size_t ws_size, hipStream_t stream) {
  const float* x = (const float*)d_in[0];
  const int* ei = (const int*)d_in[1];
  const int E = in_sizes[1] / 2;
  const float* W1 = (const float*)d_in[2];
  const float* as1 = (const float*)d_in[3];
  const float* ad1 = (const float*)d_in[4];
  const float* b1 = (const float*)d_in[5];
  const float* W2 = (const float*)d_in[6];
  const float* as2 = (const float*)d_in[7];
  const float* ad2 = (const float*)d_in[8];
  const float* b2 = (const float*)d_in[9];
  float* out = (float*)d_out;
  const int* ei0 = ei;
  const int* ei1 = ei + E;

  // workspace layout
  unsigned short* xb = (unsigned short*)d_ws;       // N*256 bf16
  unsigned short* h = xb + (size_t)NN * DIN;        // N*512 bf16
  unsigned short* wbt = h + (size_t)NN * 512;       // 512*256 bf16
  float* es1 = (float*)(wbt + 512 * DIN);           // N*4 each
  float* ed1 = es1 + NN * NH;
  float* es2 = ed1 + NN * NH;
  float* ed2 = es2 + NN * NH;
  int* deg1 = (int*)(ed2 + NN * NH);
  int* deg2 = deg1 + NN;
  int* off1 = deg2 + NN;
  int* off2 = off1 + (NN + 1);
  int* cur1 = off2 + (NN + 1);
  int* cur2 = cur1 + NN;
  int* csr1 = cur2 + NN;
  int* csr2 = csr1 + E;
  int* bsum = csr2 + E;  // 2*NBLK ints

  hipMemsetAsync(deg1, 0, 2 * NN * sizeof(int), stream);

  convert_x_kernel<<<NN * DIN / 1024, 256, 0, stream>>>(x, xb);
  wbt_kernel<<<512, 256, 0, stream>>>(W1, W2, wbt);
  degree_kernel<<<(E + 255) / 256, 256, 0, stream>>>(ei0, ei1, deg1, deg2, E);

  dim3 ggrid((NN + 127) / 128, 4);
  gemm_mfma_kernel<<<ggrid, 256, 0, stream>>>(xb, wbt, h);

  esed_kernel<<<NN * 2 / 4, 256, 0, stream>>>(h, as1, ad1, as2, ad2, es1, ed1,
                                              es2, ed2);
  bsum_kernel<<<2 * NBLK, 256, 0, stream>>>(deg1, deg2, bsum);
  bscan_kernel<<<1, 128, 0, stream>>>(bsum);
  offsets_kernel<<<2 * NBLK, 256, 0, stream>>>(deg1, deg2, bsum, off1, cur1,
                                               off2, cur2, E);
  fill_kernel<<<(E + 255) / 256, 256, 0, stream>>>(ei0, ei1, cur1, cur2, csr1,
                                                   csr2, E);

  gather_kernel<<<NN / 4, 256, 0, stream>>>(h, es1, ed1, es2, ed2, b1, b2,
                                            off1, csr1, off2, csr2, out);
}

// Round 13
// 377.379 us; speedup vs baseline: 2.2509x; 1.0044x over previous
//
#include <hip/hip_runtime.h>
#include <hip/hip_bf16.h>

#define NN 50000
#define DIN 256
#define HC 256   // H*C per direction
#define NH 4     // heads
#define CC 64    // per-head dim
#define NBLK 49  // ceil(NN/1024) chunks per direction

typedef __attribute__((ext_vector_type(8))) short short8;
typedef __attribute__((ext_vector_type(4))) float f32x4;

__device__ inline unsigned short f2bf(float f) {
  unsigned int u = __builtin_bit_cast(unsigned int, f);
  u = (u + 0x7FFF + ((u >> 16) & 1)) >> 16;  // RTNE, no NaN inputs here
  return (unsigned short)u;
}
__device__ inline float bf2f(unsigned short u) {
  return __builtin_bit_cast(float, ((unsigned int)u) << 16);
}

// ---------------------------------------------------------------------------
// x (fp32) -> xb (bf16). 12.8M elements, 4 per thread.
// ---------------------------------------------------------------------------
__global__ __launch_bounds__(256) void convert_x_kernel(
    const float* __restrict__ x, unsigned short* __restrict__ xb) {
  int i = (blockIdx.x * 256 + threadIdx.x) * 4;
  float4 v = *(const float4*)&x[i];
  ushort4 o;
  o.x = f2bf(v.x); o.y = f2bf(v.y); o.z = f2bf(v.z); o.w = f2bf(v.w);
  *(ushort4*)&xb[i] = o;
}

// ---------------------------------------------------------------------------
// WbT[n][k] = (n<256 ? W1 : W2)[k][n%256], bf16. 512x256 elements.
// ---------------------------------------------------------------------------
__global__ __launch_bounds__(256) void wbt_kernel(
    const float* __restrict__ W1, const float* __restrict__ W2,
    unsigned short* __restrict__ wbt) {
  int idx = blockIdx.x * 256 + threadIdx.x;  // 131072
  int n = idx >> 8;
  int k = idx & 255;
  float v = (n < HC) ? W1[k * HC + n] : W2[k * HC + (n - HC)];
  wbt[n * DIN + k] = f2bf(v);
}

// ---------------------------------------------------------------------------
// wproj[col][k], col = dir*8 + typ*4 + hd:  Σ_c W[k][hd*64+c] * a[hd][c]
// es/ed are linear in x: es1 = x @ (W1 a_src1) etc. 16 blocks x 256 thr.
// ---------------------------------------------------------------------------
__global__ __launch_bounds__(256) void wproj_kernel(
    const float* __restrict__ W1, const float* __restrict__ as1,
    const float* __restrict__ ad1, const float* __restrict__ W2,
    const float* __restrict__ as2, const float* __restrict__ ad2,
    unsigned short* __restrict__ wproj) {
  int idx = blockIdx.x * 256 + threadIdx.x;  // 4096
  int col = idx >> 8;
  int k = idx & 255;
  int dir = col >> 3, typ = (col >> 2) & 1, hd = col & 3;
  const float* W = dir ? W2 : W1;
  const float* a = dir ? (typ ? ad2 : as2) : (typ ? ad1 : as1);
  float s = 0.f;
#pragma unroll 8
  for (int c = 0; c < CC; ++c) s += W[k * HC + hd * CC + c] * a[hd * CC + c];
  wproj[col * DIN + k] = f2bf(s);
}

// ---------------------------------------------------------------------------
// MFMA GEMM: h[50000][512] (bf16) = xb[50000][256] @ [W1|W2] via WbT.
// 128x128 block tile, 4 waves (2x2), each wave 64x64 = 4x4 frags of 16x16x32.
// ---------------------------------------------------------------------------
__global__ __launch_bounds__(256) void gemm_mfma_kernel(
    const unsigned short* __restrict__ xb,
    const unsigned short* __restrict__ wbt, unsigned short* __restrict__ h) {
  const int tid = threadIdx.x;
  const int lane = tid & 63;
  const int wid = tid >> 6;
  const int wr = wid >> 1;  // 0..1
  const int wc = wid & 1;   // 0..1
  const int m0 = blockIdx.x * 128 + wr * 64;
  const int n0 = blockIdx.y * 128 + wc * 64;
  const int fr = lane & 15;
  const int kbase = (lane >> 4) * 8;

  f32x4 acc[4][4];
#pragma unroll
  for (int m = 0; m < 4; ++m)
#pragma unroll
    for (int n = 0; n < 4; ++n) acc[m][n] = (f32x4){0.f, 0.f, 0.f, 0.f};

  int arow[4];
  bool rowok[4];
#pragma unroll
  for (int m = 0; m < 4; ++m) {
    arow[m] = m0 + m * 16 + fr;
    rowok[m] = arow[m] < NN;
  }
  const short8 zero8 = {0, 0, 0, 0, 0, 0, 0, 0};

  for (int k0 = 0; k0 < DIN; k0 += 32) {
    short8 a[4], b[4];
#pragma unroll
    for (int m = 0; m < 4; ++m)
      a[m] = rowok[m] ? *(const short8*)&xb[(size_t)arow[m] * DIN + k0 + kbase]
                      : zero8;
#pragma unroll
    for (int n = 0; n < 4; ++n)
      b[n] = *(const short8*)&wbt[(size_t)(n0 + n * 16 + fr) * DIN + k0 + kbase];
#pragma unroll
    for (int m = 0; m < 4; ++m)
#pragma unroll
      for (int n = 0; n < 4; ++n)
        acc[m][n] = __builtin_amdgcn_mfma_f32_16x16x32_bf16(a[m], b[n],
                                                            acc[m][n], 0, 0, 0);
  }

  // C/D layout: col = lane&15, row = (lane>>4)*4 + j  [m89-verified]
#pragma unroll
  for (int m = 0; m < 4; ++m) {
#pragma unroll
    for (int j = 0; j < 4; ++j) {
      int r = m0 + m * 16 + (lane >> 4) * 4 + j;
      if (r < NN) {
#pragma unroll
        for (int n = 0; n < 4; ++n) {
          h[(size_t)r * 512 + n0 + n * 16 + fr] = f2bf(acc[m][n][j]);
        }
      }
    }
  }
}

// ---------------------------------------------------------------------------
// Skinny MFMA GEMM: es_ed[n][16] = xb[n][256] @ wproj^T. One wave per 16 rows.
// Epilogue scatters cols to es1/ed1/es2/ed2 (fp32).
// ---------------------------------------------------------------------------
__global__ __launch_bounds__(256) void esed_gemm_kernel(
    const unsigned short* __restrict__ xb,
    const unsigned short* __restrict__ wproj, float* __restrict__ es1,
    float* __restrict__ ed1, float* __restrict__ es2,
    float* __restrict__ ed2) {
  int wv = blockIdx.x * 4 + (threadIdx.x >> 6);  // 3128 waves
  int lane = threadIdx.x & 63;
  int m0 = wv * 16;
  if (m0 >= NN) return;
  const int fr = lane & 15;
  const int kbase = (lane >> 4) * 8;
  const short8 zero8 = {0, 0, 0, 0, 0, 0, 0, 0};
  f32x4 acc = (f32x4){0.f, 0.f, 0.f, 0.f};
  int arow = m0 + fr;
  bool ok = arow < NN;
#pragma unroll
  for (int k0 = 0; k0 < DIN; k0 += 32) {
    short8 a = ok ? *(const short8*)&xb[(size_t)arow * DIN + k0 + kbase] : zero8;
    short8 b = *(const short8*)&wproj[(size_t)fr * DIN + k0 + kbase];
    acc = __builtin_amdgcn_mfma_f32_16x16x32_bf16(a, b, acc, 0, 0, 0);
  }
  // C/D: col = lane&15 (= wproj col), row = (lane>>4)*4 + j
  int col = fr;
  int dir = col >> 3, typ = (col >> 2) & 1, hd = col & 3;
  float* dst = dir ? (typ ? ed2 : es2) : (typ ? ed1 : es1);
#pragma unroll
  for (int j = 0; j < 4; ++j) {
    int r = m0 + (lane >> 4) * 4 + j;
    if (r < NN) dst[r * NH + hd] = acc[j];
  }
}

// ---------------------------------------------------------------------------
// CSR build: degree -> hierarchical scan (3 small kernels) -> fill
// ---------------------------------------------------------------------------
__global__ __launch_bounds__(256) void degree_kernel(
    const int* __restrict__ ei0, const int* __restrict__ ei1,
    int* __restrict__ deg1, int* __restrict__ deg2, int E) {
  int e = blockIdx.x * 256 + threadIdx.x;
  if (e < E) {
    atomicAdd(&deg1[ei1[e]], 1);
    atomicAdd(&deg2[ei0[e]], 1);
  }
}

// stage 1: per-1024-chunk sums. grid = 2*NBLK blocks of 256.
__global__ __launch_bounds__(256) void bsum_kernel(
    const int* __restrict__ deg1, const int* __restrict__ deg2,
    int* __restrict__ bsum) {
  int b = blockIdx.x;  // 0..2*NBLK-1
  int dir = (b >= NBLK);
  int cb = dir ? b - NBLK : b;
  const int* deg = dir ? deg2 : deg1;
  int t = threadIdx.x;
  int base = cb * 1024 + t * 4;
  int s = 0;
#pragma unroll
  for (int k = 0; k < 4; ++k) {
    int i = base + k;
    if (i < NN) s += deg[i];
  }
#pragma unroll
  for (int o = 32; o; o >>= 1) s += __shfl_down(s, o);
  __shared__ int ws[4];
  int lane = t & 63, w = t >> 6;
  if (lane == 0) ws[w] = s;
  __syncthreads();
  if (t == 0) bsum[b] = ws[0] + ws[1] + ws[2] + ws[3];
}

// stage 2: exclusive scan of NBLK chunk sums per dir. 1 block, 2 waves.
__global__ __launch_bounds__(128) void bscan_kernel(int* __restrict__ bsum) {
  int t = threadIdx.x;  // 0..127
  int w = t >> 6, lane = t & 63;
  int idx = w * NBLK + lane;
  int v = (lane < NBLK) ? bsum[idx] : 0;
  int x = v;
#pragma unroll
  for (int o = 1; o < 64; o <<= 1) {
    int y = __shfl_up(x, o);
    if (lane >= o) x += y;
  }
  if (lane < NBLK) bsum[idx] = x - v;  // exclusive
}

// stage 3: write off/cur. same geometry as stage 1.
__global__ __launch_bounds__(256) void offsets_kernel(
    const int* __restrict__ deg1, const int* __restrict__ deg2,
    const int* __restrict__ bsum, int* __restrict__ off1,
    int* __restrict__ cur1, int* __restrict__ off2, int* __restrict__ cur2,
    int E) {
  int b = blockIdx.x;
  int dir = (b >= NBLK);
  int cb = dir ? b - NBLK : b;
  const int* deg = dir ? deg2 : deg1;
  int* off = dir ? off2 : off1;
  int* cur = dir ? cur2 : cur1;
  int t = threadIdx.x;
  int base = cb * 1024 + t * 4;
  int d[4];
  int s = 0;
#pragma unroll
  for (int k = 0; k < 4; ++k) {
    int i = base + k;
    d[k] = (i < NN) ? deg[i] : 0;
    s += d[k];
  }
  int lane = t & 63, w = t >> 6;
  int x = s;
#pragma unroll
  for (int o = 1; o < 64; o <<= 1) {
    int y = __shfl_up(x, o);
    if (lane >= o) x += y;
  }
  __shared__ int ws[4];
  if (lane == 63) ws[w] = x;
  __syncthreads();
  int woff = 0;
  for (int i = 0; i < w; ++i) woff += ws[i];
  int excl = bsum[b] + woff + (x - s);
#pragma unroll
  for (int k = 0; k < 4; ++k) {
    int i = base + k;
    if (i < NN) {
      off[i] = excl;
      cur[i] = excl;
      excl += d[k];
    }
  }
  if (b == 0 && t == 0) {  // both CSRs have exactly E entries
    off1[NN] = E;
    off2[NN] = E;
  }
}

__global__ __launch_bounds__(256) void fill_kernel(
    const int* __restrict__ ei0, const int* __restrict__ ei1,
    int* __restrict__ cur1, int* __restrict__ cur2, int* __restrict__ csr1,
    int* __restrict__ csr2, int E) {
  int e = blockIdx.x * 256 + threadIdx.x;
  if (e < E) {
    int s = ei0[e], d = ei1[e];
    csr1[atomicAdd(&cur1[d], 1)] = s;
    csr2[atomicAdd(&cur2[s], 1)] = d;
  }
}

// ---------------------------------------------------------------------------
// Fused gather: one wave per node, all 4 heads, both directions, with the
// two direction loops INTERLEAVED so 2 independent miss chains are in flight
// (latency-bound serial loop was the round-12 bottleneck). All branches are
// wave-uniform (n uniform per wave) -> scalar branches, no divergence.
// ---------------------------------------------------------------------------
__global__ __launch_bounds__(256) void gather_kernel(
    const unsigned short* __restrict__ h, const float* __restrict__ es1,
    const float* __restrict__ ed1, const float* __restrict__ es2,
    const float* __restrict__ ed2, const float* __restrict__ b1,
    const float* __restrict__ b2, const int* __restrict__ off1,
    const int* __restrict__ csr1, const int* __restrict__ off2,
    const int* __restrict__ csr2, float* __restrict__ out) {
  int n = blockIdx.x * 4 + (threadIdx.x >> 6);  // NN = 12500*4 exactly
  int lane = threadIdx.x & 63;
  int hd = lane >> 4;

  float ed1n = ed1[n * NH + hd];
  float ed2n = ed2[n * NH + hd];
  float e01 = es1[n * NH + hd] + ed1n;
  float e02 = es2[n * NH + hd] + ed2n;
  e01 = e01 >= 0.f ? e01 : 0.2f * e01;
  e02 = e02 >= 0.f ? e02 : 0.2f * e02;
  float w01 = __expf(e01), w02 = __expf(e02);

  size_t hbase = (size_t)n * 512 + lane * 4;
  ushort4 hv1 = *(const ushort4*)&h[hbase];
  ushort4 hv2 = *(const ushort4*)&h[hbase + HC];
  float ws1 = w01, ws2 = w02;
  float a1x = w01 * bf2f(hv1.x), a1y = w01 * bf2f(hv1.y);
  float a1z = w01 * bf2f(hv1.z), a1w = w01 * bf2f(hv1.w);
  float a2x = w02 * bf2f(hv2.x), a2y = w02 * bf2f(hv2.y);
  float a2z = w02 * bf2f(hv2.z), a2w = w02 * bf2f(hv2.w);

  int j1 = off1[n], e1 = off1[n + 1];
  int j2 = off2[n], e2 = off2[n + 1];
  while (j1 < e1 || j2 < e2) {
    if (j1 < e1) {
      int s = csr1[j1++];
      float el = es1[s * NH + hd] + ed1n;
      el = el >= 0.f ? el : 0.2f * el;
      float wg = __expf(el);
      ws1 += wg;
      ushort4 sv = *(const ushort4*)&h[(size_t)s * 512 + lane * 4];
      a1x += wg * bf2f(sv.x);
      a1y += wg * bf2f(sv.y);
      a1z += wg * bf2f(sv.z);
      a1w += wg * bf2f(sv.w);
    }
    if (j2 < e2) {
      int s = csr2[j2++];
      float el = es2[s * NH + hd] + ed2n;
      el = el >= 0.f ? el : 0.2f * el;
      float wg = __expf(el);
      ws2 += wg;
      ushort4 sv = *(const ushort4*)&h[(size_t)s * 512 + HC + lane * 4];
      a2x += wg * bf2f(sv.x);
      a2y += wg * bf2f(sv.y);
      a2z += wg * bf2f(sv.z);
      a2w += wg * bf2f(sv.w);
    }
  }
  float i1 = 1.f / ws1, i2 = 1.f / ws2;
  float4 bv1 = *(const float4*)&b1[lane * 4];
  float4 bv2 = *(const float4*)&b2[lane * 4];
  float4 o;
  o.x = 0.5f * (a1x * i1 + bv1.x + a2x * i2 + bv2.x);
  o.y = 0.5f * (a1y * i1 + bv1.y + a2y * i2 + bv2.y);
  o.z = 0.5f * (a1z * i1 + bv1.z + a2z * i2 + bv2.z);
  o.w = 0.5f * (a1w * i1 + bv1.w + a2w * i2 + bv2.w);
  *(float4*)&out[(size_t)n * HC + lane * 4] = o;
}

// ---------------------------------------------------------------------------
extern "C" void kernel_launch(void* const* d_in, const int* in_sizes, int n_in,
                              void* d_out, int out_size, void* d_ws,
                              size_t ws_size, hipStream_t stream) {
  const float* x = (const float*)d_in[0];
  const int* ei = (const int*)d_in[1];
  const int E = in_sizes[1] / 2;
  const float* W1 = (const float*)d_in[2];
  const float* as1 = (const float*)d_in[3];
  const float* ad1 = (const float*)d_in[4];
  const float* b1 = (const float*)d_in[5];
  const float* W2 = (const float*)d_in[6];
  const float* as2 = (const float*)d_in[7];
  const float* ad2 = (const float*)d_in[8];
  const float* b2 = (const float*)d_in[9];
  float* out = (float*)d_out;
  const int* ei0 = ei;
  const int* ei1 = ei + E;

  // workspace layout
  unsigned short* xb = (unsigned short*)d_ws;       // N*256 bf16
  unsigned short* h = xb + (size_t)NN * DIN;        // N*512 bf16
  unsigned short* wbt = h + (size_t)NN * 512;       // 512*256 bf16
  unsigned short* wproj = wbt + 512 * DIN;          // 16*256 bf16
  float* es1 = (float*)(wproj + 16 * DIN);          // N*4 each
  float* ed1 = es1 + NN * NH;
  float* es2 = ed1 + NN * NH;
  float* ed2 = es2 + NN * NH;
  int* deg1 = (int*)(ed2 + NN * NH);
  int* deg2 = deg1 + NN;
  int* off1 = deg2 + NN;
  int* off2 = off1 + (NN + 1);
  int* cur1 = off2 + (NN + 1);
  int* cur2 = cur1 + NN;
  int* csr1 = cur2 + NN;
  int* csr2 = csr1 + E;
  int* bsum = csr2 + E;  // 2*NBLK ints

  hipMemsetAsync(deg1, 0, 2 * NN * sizeof(int), stream);

  convert_x_kernel<<<NN * DIN / 1024, 256, 0, stream>>>(x, xb);
  wbt_kernel<<<512, 256, 0, stream>>>(W1, W2, wbt);
  wproj_kernel<<<16, 256, 0, stream>>>(W1, as1, ad1, W2, as2, ad2, wproj);
  degree_kernel<<<(E + 255) / 256, 256, 0, stream>>>(ei0, ei1, deg1, deg2, E);

  dim3 ggrid((NN + 127) / 128, 4);
  gemm_mfma_kernel<<<ggrid, 256, 0, stream>>>(xb, wbt, h);
  esed_gemm_kernel<<<(NN / 16 + 3) / 4, 256, 0, stream>>>(xb, wproj, es1, ed1,
                                                          es2, ed2);

  bsum_kernel<<<2 * NBLK, 256, 0, stream>>>(deg1, deg2, bsum);
  bscan_kernel<<<1, 128, 0, stream>>>(bsum);
  offsets_kernel<<<2 * NBLK, 256, 0, stream>>>(deg1, deg2, bsum, off1, cur1,
                                               off2, cur2, E);
  fill_kernel<<<(E + 255) / 256, 256, 0, stream>>>(ei0, ei1, cur1, cur2, csr1,
                                                   csr2, E);

  gather_kernel<<<NN / 4, 256, 0, stream>>>(h, es1, ed1, es2, ed2, b1, b2,
                                            off1, csr1, off2, csr2, out);
}